// Round 1
// baseline (360.442 us; speedup 1.0000x reference)
//
#include <hip/hip_runtime.h>
#include <hip/hip_bf16.h>
#include <stdint.h>

typedef __attribute__((ext_vector_type(8))) __bf16 bf16x8;
typedef __attribute__((ext_vector_type(4))) float f32x4;
typedef __hip_bfloat16 bf16;

#define GLDS(g, l) __builtin_amdgcn_global_load_lds( \
    (const __attribute__((address_space(1))) void*)(g), \
    (__attribute__((address_space(3))) void*)(l), 16, 0, 0)

// ---------------- workspace layout (bytes) ----------------
#define OFF_XB     ((size_t)0)          // 4096*1024 bf16 = 8388608  (reused as attnb)
#define OFF_WQKVB  ((size_t)8388608)    // 3072*1024 bf16 = 6291456
#define OFF_WOB    ((size_t)14680064)   // 1024*1024 bf16 = 2097152
#define OFF_QB     ((size_t)16777216)   // 32*2048*64 bf16 = 8388608
#define OFF_KB     ((size_t)25165824)
#define OFF_VTB    ((size_t)33554432)
#define OFF_CS     ((size_t)41943040)   // 2048*32 f32 = 262144
#define OFF_SN     ((size_t)42205184)

// ---------------- fp32 -> bf16 conversion ----------------
__global__ void prep_kernel(const float* __restrict__ x, const float* __restrict__ wq,
                            const float* __restrict__ wk, const float* __restrict__ wv,
                            const float* __restrict__ wo,
                            bf16* __restrict__ xb, bf16* __restrict__ wqkvb,
                            bf16* __restrict__ wob)
{
    const int region = blockIdx.y;
    const float* src;
    bf16* dst;
    int count;
    switch (region) {
        case 0:  src = x;  dst = xb;              count = 4096 * 1024; break;
        case 1:  src = wq; dst = wqkvb;           count = 1024 * 1024; break;
        case 2:  src = wk; dst = wqkvb + 1048576; count = 1024 * 1024; break;
        case 3:  src = wv; dst = wqkvb + 2097152; count = 1024 * 1024; break;
        default: src = wo; dst = wob;             count = 1024 * 1024; break;
    }
    const int i = (blockIdx.x * 256 + threadIdx.x) * 4;
    if (i >= count) return;
    const float4 v = *(const float4*)(src + i);
    union { bf16 h[4]; short4 s4; } u;
    u.h[0] = __float2bfloat16(v.x);
    u.h[1] = __float2bfloat16(v.y);
    u.h[2] = __float2bfloat16(v.z);
    u.h[3] = __float2bfloat16(v.w);
    *(short4*)(dst + i) = u.s4;
}

// ---------------- RoPE cos/sin table: [s][i], i = d/2 in [0,32) ----------------
__global__ void rope_table_kernel(const int* __restrict__ pos, const void* __restrict__ theta_p,
                                  float* __restrict__ cst, float* __restrict__ snt)
{
    const int t = blockIdx.x * 256 + threadIdx.x;   // 2048*32 = 65536
    const int s = t >> 5, i = t & 31;
    const int ti = ((const int*)theta_p)[0];
    const float theta = (ti > 0 && ti < 100000000) ? (float)ti : ((const float*)theta_p)[0];
    const float fr = expf(-(float)i * (1.0f / 32.0f) * logf(theta));
    const float ang = (float)pos[s] * fr;
    cst[t] = cosf(ang);
    snt[t] = sinf(ang);
}

// ---------------- GEMM: C[M,N] = A[M,K] * B[N,K]^T, bf16 in, fp32 acc ----------------
// 128x128 tile, BK=32, 4 waves (2x2), 4x4 16x16x32 fragments per wave.
// MODE 0: QKV epilogue (RoPE + scatter). MODE 1: fp32 row-major store.
template<int MODE>
__global__ __launch_bounds__(256) void gemm_bt(
    const bf16* __restrict__ A, const bf16* __restrict__ B,
    const int K, const int N,
    float* __restrict__ outf,
    bf16* __restrict__ qb, bf16* __restrict__ kb, bf16* __restrict__ vtb,
    const float* __restrict__ cst, const float* __restrict__ snt)
{
    __shared__ __align__(16) bf16 Asl[128 * 32];
    __shared__ __align__(16) bf16 Bsl[128 * 32];
    const int tid = threadIdx.x;
    const int wave = tid >> 6, lane = tid & 63;
    const int lr = lane & 15, lk = lane >> 4;
    const int m0 = blockIdx.x * 128;
    const int n0 = blockIdx.y * 128;
    const int wm = (wave >> 1) * 64;
    const int wn = (wave & 1) * 64;
    const int srow = tid >> 2, sseg = tid & 3;

    f32x4 acc[4][4] = {};

    const bf16* aRow = A + (size_t)(m0 + srow) * K + sseg * 8;
    const bf16* bRow = B + (size_t)(n0 + srow) * K + sseg * 8;
    char* lA = (char*)Asl + tid * 16;
    char* lB = (char*)Bsl + tid * 16;
    const size_t rowK64 = (size_t)64 * K;

    for (int k0 = 0; k0 < K; k0 += 32) {
        GLDS(aRow + k0, lA);
        GLDS(aRow + k0 + rowK64, lA + 4096);
        GLDS(bRow + k0, lB);
        GLDS(bRow + k0 + rowK64, lB + 4096);
        __syncthreads();
        bf16x8 af[4], bfr[4];
#pragma unroll
        for (int i = 0; i < 4; ++i)
            af[i] = *(const bf16x8*)(Asl + (wm + i * 16 + lr) * 32 + lk * 8);
#pragma unroll
        for (int j = 0; j < 4; ++j)
            bfr[j] = *(const bf16x8*)(Bsl + (wn + j * 16 + lr) * 32 + lk * 8);
#pragma unroll
        for (int i = 0; i < 4; ++i)
#pragma unroll
            for (int j = 0; j < 4; ++j)
                acc[i][j] = __builtin_amdgcn_mfma_f32_16x16x32_bf16(af[i], bfr[j], acc[i][j], 0, 0, 0);
        __syncthreads();
    }

    if constexpr (MODE == 1) {
#pragma unroll
        for (int i = 0; i < 4; ++i)
#pragma unroll
            for (int j = 0; j < 4; ++j)
#pragma unroll
                for (int r = 0; r < 4; ++r) {
                    const int row = m0 + wm + i * 16 + lk * 4 + r;
                    const int col = n0 + wn + j * 16 + lr;
                    outf[(size_t)row * N + col] = acc[i][j][r];
                }
    } else {
        const int matn = n0 >> 10;   // 0=Q 1=K 2=V, uniform per block
#pragma unroll
        for (int i = 0; i < 4; ++i)
#pragma unroll
            for (int j = 0; j < 4; ++j)
#pragma unroll
                for (int r = 0; r < 4; ++r) {
                    const int row = m0 + wm + i * 16 + lk * 4 + r;
                    const int col = n0 + wn + j * 16 + lr;
                    float v = acc[i][j][r];
                    float p = __shfl_xor(v, 1);        // RoPE pair partner
                    const int e = col & 1023;
                    const int h = e >> 6;
                    const int dd = e & 63;
                    const int b = row >> 11;
                    const int s = row & 2047;
                    const size_t bhi = (size_t)(b * 16 + h);
                    if (matn == 2) {
                        vtb[(bhi * 64 + dd) * 2048 + s] = __float2bfloat16(v);
                    } else {
                        const float cs = cst[s * 32 + (dd >> 1)];
                        const float sn = snt[s * 32 + (dd >> 1)];
                        const float rv = (dd & 1) ? (p * sn + v * cs) : (v * cs - p * sn);
                        if (matn == 0)
                            qb[(bhi * 2048 + s) * 64 + dd] = __float2bfloat16(rv * 0.125f);
                        else
                            kb[(bhi * 2048 + s) * 64 + dd] = __float2bfloat16(rv);
                    }
                }
    }
}

// ---------------- causal flash attention ----------------
// grid (32 q-tiles, 32 bh). 4 independent waves per block, 16 q-rows each.
// Q,K: (bh, s, 64) bf16. V: transposed (bh, 64, s) bf16. Out: (b, s, h*64+d) bf16.
__global__ __launch_bounds__(256) void attn_kernel(
    const bf16* __restrict__ qb, const bf16* __restrict__ kb,
    const bf16* __restrict__ vtb, bf16* __restrict__ attnb)
{
    __shared__ __align__(16) bf16 Pl[4][16][72];  // per-wave P strip, padded rows (144B)
    const int tid = threadIdx.x;
    const int wave = tid >> 6, lane = tid & 63;
    const int lr = lane & 15, lk = lane >> 4;
    const int qt = gridDim.x - 1 - blockIdx.x;    // long blocks first
    const int bh = blockIdx.y;
    const int q0 = qt * 64;
    const int qw = q0 + wave * 16;

    const bf16* Qp = qb + (size_t)bh * 2048 * 64;
    const bf16* Kp = kb + (size_t)bh * 2048 * 64;
    const bf16* Vp = vtb + (size_t)bh * 64 * 2048;

    bf16x8 qf[2];
#pragma unroll
    for (int ks = 0; ks < 2; ++ks)
        qf[ks] = *(const bf16x8*)(Qp + (qw + lr) * 64 + ks * 32 + lk * 8);

    float mrow[4], lrow[4];
    f32x4 acc_o[4] = {};
#pragma unroll
    for (int r = 0; r < 4; ++r) { mrow[r] = -1e30f; lrow[r] = 0.f; }

    for (int kt = 0; kt <= qt; ++kt) {
        const int kv0 = kt * 64;
        f32x4 sc[4] = {};
#pragma unroll
        for (int ks = 0; ks < 2; ++ks)
#pragma unroll
            for (int j = 0; j < 4; ++j) {
                bf16x8 kf = *(const bf16x8*)(Kp + (kv0 + j * 16 + lr) * 64 + ks * 32 + lk * 8);
                sc[j] = __builtin_amdgcn_mfma_f32_16x16x32_bf16(qf[ks], kf, sc[j], 0, 0, 0);
            }
        if (kt == qt) {   // diagonal tile: per-element causal mask
#pragma unroll
            for (int j = 0; j < 4; ++j)
#pragma unroll
                for (int r = 0; r < 4; ++r)
                    if (kv0 + j * 16 + lr > qw + lk * 4 + r) sc[j][r] = -1e30f;
        }
        float al[4];
#pragma unroll
        for (int r = 0; r < 4; ++r) {
            float mt = fmaxf(fmaxf(sc[0][r], sc[1][r]), fmaxf(sc[2][r], sc[3][r]));
            mt = fmaxf(mt, __shfl_xor(mt, 1));
            mt = fmaxf(mt, __shfl_xor(mt, 2));
            mt = fmaxf(mt, __shfl_xor(mt, 4));
            mt = fmaxf(mt, __shfl_xor(mt, 8));
            const float mn = fmaxf(mrow[r], mt);
            al[r] = __expf(mrow[r] - mn);
            mrow[r] = mn;
        }
        float rs[4] = {0.f, 0.f, 0.f, 0.f};
#pragma unroll
        for (int j = 0; j < 4; ++j)
#pragma unroll
            for (int r = 0; r < 4; ++r) {
                const float pv = __expf(sc[j][r] - mrow[r]);
                rs[r] += pv;
                Pl[wave][lk * 4 + r][j * 16 + lr] = __float2bfloat16(pv);
            }
#pragma unroll
        for (int r = 0; r < 4; ++r) {
            rs[r] += __shfl_xor(rs[r], 1);
            rs[r] += __shfl_xor(rs[r], 2);
            rs[r] += __shfl_xor(rs[r], 4);
            rs[r] += __shfl_xor(rs[r], 8);
            lrow[r] = lrow[r] * al[r] + rs[r];
        }
#pragma unroll
        for (int j = 0; j < 4; ++j)
#pragma unroll
            for (int r = 0; r < 4; ++r) acc_o[j][r] *= al[r];
#pragma unroll
        for (int ks = 0; ks < 2; ++ks) {
            const bf16x8 pf = *(const bf16x8*)((const char*)&Pl[wave][lr][0] + ks * 64 + lk * 16);
#pragma unroll
            for (int j = 0; j < 4; ++j) {
                bf16x8 vf = *(const bf16x8*)(Vp + (j * 16 + lr) * 2048 + kv0 + ks * 32 + lk * 8);
                acc_o[j] = __builtin_amdgcn_mfma_f32_16x16x32_bf16(pf, vf, acc_o[j], 0, 0, 0);
            }
        }
    }

    const int b = bh >> 4, h = bh & 15;
#pragma unroll
    for (int r = 0; r < 4; ++r) {
        const int qq = qw + lk * 4 + r;
        const float inv = 1.0f / lrow[r];
#pragma unroll
        for (int j = 0; j < 4; ++j)
            attnb[((size_t)(b * 2048 + qq)) * 1024 + h * 64 + j * 16 + lr] =
                __float2bfloat16(acc_o[j][r] * inv);
    }
}

// ---------------- launch ----------------
extern "C" void kernel_launch(void* const* d_in, const int* in_sizes, int n_in,
                              void* d_out, int out_size, void* d_ws, size_t ws_size,
                              hipStream_t stream)
{
    const float* x   = (const float*)d_in[0];
    const float* wq  = (const float*)d_in[1];
    const float* wk  = (const float*)d_in[2];
    const float* wv  = (const float*)d_in[3];
    const float* wo  = (const float*)d_in[4];
    const int*   pos = (const int*)d_in[5];
    const void* theta = d_in[6];

    char* ws = (char*)d_ws;
    bf16* xb    = (bf16*)(ws + OFF_XB);
    bf16* attnb = (bf16*)(ws + OFF_XB);    // reuse: xb consumed before attn writes
    bf16* wqkvb = (bf16*)(ws + OFF_WQKVB);
    bf16* wob   = (bf16*)(ws + OFF_WOB);
    bf16* qb    = (bf16*)(ws + OFF_QB);
    bf16* kb    = (bf16*)(ws + OFF_KB);
    bf16* vtb   = (bf16*)(ws + OFF_VTB);
    float* cst  = (float*)(ws + OFF_CS);
    float* snt  = (float*)(ws + OFF_SN);

    prep_kernel<<<dim3(4096, 5), 256, 0, stream>>>(x, wq, wk, wv, wo, xb, wqkvb, wob);
    rope_table_kernel<<<256, 256, 0, stream>>>(pos, theta, cst, snt);
    gemm_bt<0><<<dim3(32, 24), 256, 0, stream>>>(xb, wqkvb, 1024, 3072, nullptr,
                                                 qb, kb, vtb, cst, snt);
    attn_kernel<<<dim3(32, 32), 256, 0, stream>>>(qb, kb, vtb, attnb);
    gemm_bt<1><<<dim3(32, 8), 256, 0, stream>>>(attnb, wob, 1024, 1024, (float*)d_out,
                                                nullptr, nullptr, nullptr, nullptr, nullptr);
}

// Round 2
// 195.866 us; speedup vs baseline: 1.8403x; 1.8403x over previous
//
#include <hip/hip_runtime.h>
#include <hip/hip_bf16.h>
#include <stdint.h>

typedef __attribute__((ext_vector_type(8))) __bf16 bf16x8;
typedef __attribute__((ext_vector_type(4))) float f32x4;
typedef __hip_bfloat16 bf16;

#define GLDS(g, l) __builtin_amdgcn_global_load_lds( \
    (const __attribute__((address_space(1))) void*)(g), \
    (__attribute__((address_space(3))) void*)(l), 16, 0, 0)

// ---------------- workspace layout (bytes) ----------------
#define OFF_XB     ((size_t)0)          // 4096*1024 bf16 = 8388608  (reused as attnb)
#define OFF_WQKVB  ((size_t)8388608)    // 3072*1024 bf16 = 6291456
#define OFF_WOB    ((size_t)14680064)   // 1024*1024 bf16 = 2097152
#define OFF_QB     ((size_t)16777216)   // 32*2048*64 bf16 = 8388608
#define OFF_KB     ((size_t)25165824)
#define OFF_VTB    ((size_t)33554432)
#define OFF_CS     ((size_t)41943040)   // 2048*32 f32 = 262144
#define OFF_SN     ((size_t)42205184)

// ---------------- fp32 -> bf16 conversion ----------------
__global__ void prep_kernel(const float* __restrict__ x, const float* __restrict__ wq,
                            const float* __restrict__ wk, const float* __restrict__ wv,
                            const float* __restrict__ wo,
                            bf16* __restrict__ xb, bf16* __restrict__ wqkvb,
                            bf16* __restrict__ wob)
{
    const int region = blockIdx.y;
    const float* src;
    bf16* dst;
    int count;
    switch (region) {
        case 0:  src = x;  dst = xb;              count = 4096 * 1024; break;
        case 1:  src = wq; dst = wqkvb;           count = 1024 * 1024; break;
        case 2:  src = wk; dst = wqkvb + 1048576; count = 1024 * 1024; break;
        case 3:  src = wv; dst = wqkvb + 2097152; count = 1024 * 1024; break;
        default: src = wo; dst = wob;             count = 1024 * 1024; break;
    }
    const int i = (blockIdx.x * 256 + threadIdx.x) * 4;
    if (i >= count) return;
    const float4 v = *(const float4*)(src + i);
    union { bf16 h[4]; short4 s4; } u;
    u.h[0] = __float2bfloat16(v.x);
    u.h[1] = __float2bfloat16(v.y);
    u.h[2] = __float2bfloat16(v.z);
    u.h[3] = __float2bfloat16(v.w);
    *(short4*)(dst + i) = u.s4;
}

// ---------------- RoPE cos/sin table: [s][i], i = d/2 in [0,32) ----------------
__global__ void rope_table_kernel(const int* __restrict__ pos, const void* __restrict__ theta_p,
                                  float* __restrict__ cst, float* __restrict__ snt)
{
    const int t = blockIdx.x * 256 + threadIdx.x;   // 2048*32 = 65536
    const int s = t >> 5, i = t & 31;
    const int ti = ((const int*)theta_p)[0];
    const float theta = (ti > 0 && ti < 100000000) ? (float)ti : ((const float*)theta_p)[0];
    const float fr = expf(-(float)i * (1.0f / 32.0f) * logf(theta));
    const float ang = (float)pos[s] * fr;
    cst[t] = cosf(ang);
    snt[t] = sinf(ang);
}

// ---------------- GEMM: C[M,N] = A[M,K] * B[N,K]^T, bf16 in, fp32 acc ----------------
// 128x128 tile, BK=32, 4 waves (2x2), 4x4 16x16x32 fragments per wave.
// MODE 0: QKV epilogue (RoPE + scatter). MODE 1: fp32 row-major store.
template<int MODE>
__global__ __launch_bounds__(256) void gemm_bt(
    const bf16* __restrict__ A, const bf16* __restrict__ B,
    const int K, const int N,
    float* __restrict__ outf,
    bf16* __restrict__ qb, bf16* __restrict__ kb, bf16* __restrict__ vtb,
    const float* __restrict__ cst, const float* __restrict__ snt)
{
    __shared__ __align__(16) bf16 Asl[128 * 32];
    __shared__ __align__(16) bf16 Bsl[128 * 32];
    const int tid = threadIdx.x;
    const int wave = tid >> 6, lane = tid & 63;
    const int lr = lane & 15, lk = lane >> 4;
    const int m0 = blockIdx.x * 128;
    const int n0 = blockIdx.y * 128;
    const int wm = (wave >> 1) * 64;
    const int wn = (wave & 1) * 64;
    const int srow = tid >> 2, sseg = tid & 3;

    f32x4 acc[4][4] = {};

    const bf16* aRow = A + (size_t)(m0 + srow) * K + sseg * 8;
    const bf16* bRow = B + (size_t)(n0 + srow) * K + sseg * 8;
    char* lA = (char*)Asl + tid * 16;
    char* lB = (char*)Bsl + tid * 16;
    const size_t rowK64 = (size_t)64 * K;

    for (int k0 = 0; k0 < K; k0 += 32) {
        GLDS(aRow + k0, lA);
        GLDS(aRow + k0 + rowK64, lA + 4096);
        GLDS(bRow + k0, lB);
        GLDS(bRow + k0 + rowK64, lB + 4096);
        __syncthreads();
        bf16x8 af[4], bfr[4];
#pragma unroll
        for (int i = 0; i < 4; ++i)
            af[i] = *(const bf16x8*)(Asl + (wm + i * 16 + lr) * 32 + lk * 8);
#pragma unroll
        for (int j = 0; j < 4; ++j)
            bfr[j] = *(const bf16x8*)(Bsl + (wn + j * 16 + lr) * 32 + lk * 8);
#pragma unroll
        for (int i = 0; i < 4; ++i)
#pragma unroll
            for (int j = 0; j < 4; ++j)
                acc[i][j] = __builtin_amdgcn_mfma_f32_16x16x32_bf16(af[i], bfr[j], acc[i][j], 0, 0, 0);
        __syncthreads();
    }

    if constexpr (MODE == 1) {
#pragma unroll
        for (int i = 0; i < 4; ++i)
#pragma unroll
            for (int j = 0; j < 4; ++j)
#pragma unroll
                for (int r = 0; r < 4; ++r) {
                    const int row = m0 + wm + i * 16 + lk * 4 + r;
                    const int col = n0 + wn + j * 16 + lr;
                    outf[(size_t)row * N + col] = acc[i][j][r];
                }
    } else {
        const int matn = n0 >> 10;   // 0=Q 1=K 2=V, uniform per block
#pragma unroll
        for (int i = 0; i < 4; ++i)
#pragma unroll
            for (int j = 0; j < 4; ++j)
#pragma unroll
                for (int r = 0; r < 4; ++r) {
                    const int row = m0 + wm + i * 16 + lk * 4 + r;
                    const int col = n0 + wn + j * 16 + lr;
                    float v = acc[i][j][r];
                    float p = __shfl_xor(v, 1);        // RoPE pair partner
                    const int e = col & 1023;
                    const int h = e >> 6;
                    const int dd = e & 63;
                    const int b = row >> 11;
                    const int s = row & 2047;
                    const size_t bhi = (size_t)(b * 16 + h);
                    if (matn == 2) {
                        vtb[(bhi * 64 + dd) * 2048 + s] = __float2bfloat16(v);
                    } else {
                        const float cs = cst[s * 32 + (dd >> 1)];
                        const float sn = snt[s * 32 + (dd >> 1)];
                        const float rv = (dd & 1) ? (p * sn + v * cs) : (v * cs - p * sn);
                        if (matn == 0)
                            qb[(bhi * 2048 + s) * 64 + dd] = __float2bfloat16(rv * 0.125f);
                        else
                            kb[(bhi * 2048 + s) * 64 + dd] = __float2bfloat16(rv);
                    }
                }
    }
}

// ---------------- causal flash attention ----------------
// grid (32 q-tiles, 32 bh). 4 waves/block share LDS-staged K/V tiles
// (global_load_lds width-16, double-buffered, counted vmcnt prefetch).
// K stored XOR-swizzled via pre-swizzled global source (m173 pattern).
// Q,K: (bh, s, 64) bf16. V: transposed (bh, 64, s) bf16. Out: (b, s, h*64+d) bf16.
__global__ __launch_bounds__(256) void attn_kernel(
    const bf16* __restrict__ qb, const bf16* __restrict__ kb,
    const bf16* __restrict__ vtb, bf16* __restrict__ attnb)
{
    __shared__ __align__(16) bf16 Kl[2][64 * 64];
    __shared__ __align__(16) bf16 Vl[2][64 * 64];
    __shared__ __align__(16) bf16 Pl[4][16][72];  // per-wave P strip, padded rows (144B)
    const int tid = threadIdx.x;
    const int wave = tid >> 6, lane = tid & 63;
    const int lr = lane & 15, lk = lane >> 4;
    const int qt = gridDim.x - 1 - blockIdx.x;    // long blocks first
    const int bh = blockIdx.y;
    const int qw = qt * 64 + wave * 16;

    const bf16* Qp = qb + (size_t)bh * 2048 * 64;
    const bf16* Kp = kb + (size_t)bh * 2048 * 64;
    const bf16* Vp = vtb + (size_t)bh * 64 * 2048;

    // staging geometry: 256 threads x 16B = 4KB = 32 rows of 128B per GLDS inst
    const int srow = tid >> 3;                     // 0..31
    const int sseg = tid & 7;
    const int sw16 = (sseg ^ (srow & 7)) * 16;     // pre-swizzled byte offset in row
    const char* kg = (const char*)Kp + (size_t)srow * 128 + sw16;
    const char* vg = (const char*)Vp + (size_t)srow * 4096 + sw16;

#define STAGE(kt_, c_) do {                                              \
        const char* kgt = kg + (size_t)(kt_) * 8192;                     \
        GLDS(kgt,              &Kl[c_][0] + tid * 8);                    \
        GLDS(kgt + 32 * 128,   &Kl[c_][0] + 2048 + tid * 8);             \
        const char* vgt = vg + (size_t)(kt_) * 128;                      \
        GLDS(vgt,              &Vl[c_][0] + tid * 8);                    \
        GLDS(vgt + 32 * 4096,  &Vl[c_][0] + 2048 + tid * 8);             \
    } while (0)

    bf16x8 qf[2];
#pragma unroll
    for (int ks = 0; ks < 2; ++ks)
        qf[ks] = *(const bf16x8*)(Qp + (qw + lr) * 64 + ks * 32 + lk * 8);

    float mrow[4], plsum[4];
    f32x4 acc_o[4] = {};
#pragma unroll
    for (int r = 0; r < 4; ++r) { mrow[r] = -1e30f; plsum[r] = 0.f; }

    STAGE(0, 0);   // prologue prefetch

    for (int kt = 0; kt <= qt; ++kt) {
        const int c = kt & 1;
        const int kv0 = kt * 64;
        if (kt < qt) {
            STAGE(kt + 1, c ^ 1);
            asm volatile("s_waitcnt vmcnt(4)" ::: "memory");  // drain this tile, keep prefetch in flight
        } else {
            asm volatile("s_waitcnt vmcnt(0)" ::: "memory");
        }
        __builtin_amdgcn_s_barrier();
        __builtin_amdgcn_sched_barrier(0);
        const bf16* Kc = &Kl[c][0];
        const bf16* Vc = &Vl[c][0];

        f32x4 sc[4] = {};
#pragma unroll
        for (int ks = 0; ks < 2; ++ks)
#pragma unroll
            for (int j = 0; j < 4; ++j) {
                const int row = j * 16 + lr;
                bf16x8 kf = *(const bf16x8*)(Kc + row * 64 + ((ks * 32 + lk * 8) ^ ((row & 7) * 8)));
                sc[j] = __builtin_amdgcn_mfma_f32_16x16x32_bf16(qf[ks], kf, sc[j], 0, 0, 0);
            }
        if (kt == qt) {   // diagonal tile: per-element causal mask
#pragma unroll
            for (int j = 0; j < 4; ++j)
#pragma unroll
                for (int r = 0; r < 4; ++r)
                    if (kv0 + j * 16 + lr > qw + lk * 4 + r) sc[j][r] = -1e30f;
        }
        float al[4];
#pragma unroll
        for (int r = 0; r < 4; ++r) {
            float mt = fmaxf(fmaxf(sc[0][r], sc[1][r]), fmaxf(sc[2][r], sc[3][r]));
            mt = fmaxf(mt, __shfl_xor(mt, 1));
            mt = fmaxf(mt, __shfl_xor(mt, 2));
            mt = fmaxf(mt, __shfl_xor(mt, 4));
            mt = fmaxf(mt, __shfl_xor(mt, 8));
            const float mn = fmaxf(mrow[r], mt);
            al[r] = __expf(mrow[r] - mn);
            mrow[r] = mn;
        }
#pragma unroll
        for (int j = 0; j < 4; ++j)
#pragma unroll
            for (int r = 0; r < 4; ++r) {
                const float pv = __expf(sc[j][r] - mrow[r]);
                plsum[r] = (j == 0) ? (plsum[r] * al[r] + pv) : (plsum[r] + pv);
                Pl[wave][lk * 4 + r][j * 16 + lr] = __float2bfloat16(pv);
            }
#pragma unroll
        for (int j = 0; j < 4; ++j)
#pragma unroll
            for (int r = 0; r < 4; ++r) acc_o[j][r] *= al[r];
#pragma unroll
        for (int ks = 0; ks < 2; ++ks) {
            const bf16x8 pf = *(const bf16x8*)((const char*)&Pl[wave][lr][0] + ks * 64 + lk * 16);
#pragma unroll
            for (int j = 0; j < 4; ++j) {
                const int row = j * 16 + lr;
                bf16x8 vf = *(const bf16x8*)(Vc + row * 64 + ((ks * 32 + lk * 8) ^ ((row & 7) * 8)));
                acc_o[j] = __builtin_amdgcn_mfma_f32_16x16x32_bf16(pf, vf, acc_o[j], 0, 0, 0);
            }
        }
        __builtin_amdgcn_sched_barrier(0);
        __builtin_amdgcn_s_barrier();   // all reads of buf c done before next stage overwrites
    }

    const int b = bh >> 4, h = bh & 15;
#pragma unroll
    for (int r = 0; r < 4; ++r) {
        float s = plsum[r];
        s += __shfl_xor(s, 1);
        s += __shfl_xor(s, 2);
        s += __shfl_xor(s, 4);
        s += __shfl_xor(s, 8);
        const int qq = qw + lk * 4 + r;
        const float inv = 1.0f / s;
#pragma unroll
        for (int j = 0; j < 4; ++j)
            attnb[((size_t)(b * 2048 + qq)) * 1024 + h * 64 + j * 16 + lr] =
                __float2bfloat16(acc_o[j][r] * inv);
    }
#undef STAGE
}

// ---------------- launch ----------------
extern "C" void kernel_launch(void* const* d_in, const int* in_sizes, int n_in,
                              void* d_out, int out_size, void* d_ws, size_t ws_size,
                              hipStream_t stream)
{
    const float* x   = (const float*)d_in[0];
    const float* wq  = (const float*)d_in[1];
    const float* wk  = (const float*)d_in[2];
    const float* wv  = (const float*)d_in[3];
    const float* wo  = (const float*)d_in[4];
    const int*   pos = (const int*)d_in[5];
    const void* theta = d_in[6];

    char* ws = (char*)d_ws;
    bf16* xb    = (bf16*)(ws + OFF_XB);
    bf16* attnb = (bf16*)(ws + OFF_XB);    // reuse: xb consumed before attn writes
    bf16* wqkvb = (bf16*)(ws + OFF_WQKVB);
    bf16* wob   = (bf16*)(ws + OFF_WOB);
    bf16* qb    = (bf16*)(ws + OFF_QB);
    bf16* kb    = (bf16*)(ws + OFF_KB);
    bf16* vtb   = (bf16*)(ws + OFF_VTB);
    float* cst  = (float*)(ws + OFF_CS);
    float* snt  = (float*)(ws + OFF_SN);

    prep_kernel<<<dim3(4096, 5), 256, 0, stream>>>(x, wq, wk, wv, wo, xb, wqkvb, wob);
    rope_table_kernel<<<256, 256, 0, stream>>>(pos, theta, cst, snt);
    gemm_bt<0><<<dim3(32, 24), 256, 0, stream>>>(xb, wqkvb, 1024, 3072, nullptr,
                                                 qb, kb, vtb, cst, snt);
    attn_kernel<<<dim3(32, 32), 256, 0, stream>>>(qb, kb, vtb, attnb);
    gemm_bt<1><<<dim3(32, 8), 256, 0, stream>>>(attnb, wob, 1024, 1024, (float*)d_out,
                                                nullptr, nullptr, nullptr, nullptr, nullptr);
}

// Round 3
// 153.643 us; speedup vs baseline: 2.3460x; 1.2748x over previous
//
#include <hip/hip_runtime.h>
#include <hip/hip_bf16.h>
#include <stdint.h>

typedef __attribute__((ext_vector_type(8))) __bf16 bf16x8;
typedef __attribute__((ext_vector_type(4))) float f32x4;
typedef __hip_bfloat16 bf16;

#define GLDS(g, l) __builtin_amdgcn_global_load_lds( \
    (const __attribute__((address_space(1))) void*)(g), \
    (__attribute__((address_space(3))) void*)(l), 16, 0, 0)

// ---------------- workspace layout (bytes) ----------------
#define OFF_XB     ((size_t)0)          // 4096*1024 bf16 = 8388608  (reused as attnb)
#define OFF_WQKVB  ((size_t)8388608)    // 3072*1024 bf16 = 6291456
#define OFF_WOB    ((size_t)14680064)   // 1024*1024 bf16 = 2097152
#define OFF_QB     ((size_t)16777216)   // 32*2048*64 bf16 = 8388608
#define OFF_KB     ((size_t)25165824)
#define OFF_VTB    ((size_t)33554432)
#define OFF_CS     ((size_t)41943040)   // 2048*32 f32 = 262144
#define OFF_SN     ((size_t)42205184)

// ---------------- fp32 -> bf16 conversion ----------------
__global__ void prep_kernel(const float* __restrict__ x, const float* __restrict__ wq,
                            const float* __restrict__ wk, const float* __restrict__ wv,
                            const float* __restrict__ wo,
                            bf16* __restrict__ xb, bf16* __restrict__ wqkvb,
                            bf16* __restrict__ wob)
{
    const int region = blockIdx.y;
    const float* src;
    bf16* dst;
    int count;
    switch (region) {
        case 0:  src = x;  dst = xb;              count = 4096 * 1024; break;
        case 1:  src = wq; dst = wqkvb;           count = 1024 * 1024; break;
        case 2:  src = wk; dst = wqkvb + 1048576; count = 1024 * 1024; break;
        case 3:  src = wv; dst = wqkvb + 2097152; count = 1024 * 1024; break;
        default: src = wo; dst = wob;             count = 1024 * 1024; break;
    }
    const int i = (blockIdx.x * 256 + threadIdx.x) * 4;
    if (i >= count) return;
    const float4 v = *(const float4*)(src + i);
    union { bf16 h[4]; short4 s4; } u;
    u.h[0] = __float2bfloat16(v.x);
    u.h[1] = __float2bfloat16(v.y);
    u.h[2] = __float2bfloat16(v.z);
    u.h[3] = __float2bfloat16(v.w);
    *(short4*)(dst + i) = u.s4;
}

// ---------------- RoPE cos/sin table: [s][i], i = d/2 in [0,32) ----------------
__global__ void rope_table_kernel(const int* __restrict__ pos, const void* __restrict__ theta_p,
                                  float* __restrict__ cst, float* __restrict__ snt)
{
    const int t = blockIdx.x * 256 + threadIdx.x;   // 2048*32 = 65536
    const int s = t >> 5, i = t & 31;
    const int ti = ((const int*)theta_p)[0];
    const float theta = (ti > 0 && ti < 100000000) ? (float)ti : ((const float*)theta_p)[0];
    const float fr = expf(-(float)i * (1.0f / 32.0f) * logf(theta));
    const float ang = (float)pos[s] * fr;
    cst[t] = cosf(ang);
    snt[t] = sinf(ang);
}

// ---------------- GEMM: C[M,N] = A[M,K] * B[N,K]^T, bf16 in, fp32 acc ----------------
// 128x128 tile, BK=32, 4 waves (2x2), 4x4 16x16x32 fragments per wave.
// MODE 0: QKV epilogue (RoPE + scatter). MODE 1: fp32 row-major store.
template<int MODE>
__global__ __launch_bounds__(256) void gemm_bt(
    const bf16* __restrict__ A, const bf16* __restrict__ B,
    const int K, const int N,
    float* __restrict__ outf,
    bf16* __restrict__ qb, bf16* __restrict__ kb, bf16* __restrict__ vtb,
    const float* __restrict__ cst, const float* __restrict__ snt)
{
    __shared__ __align__(16) bf16 Asl[128 * 32];
    __shared__ __align__(16) bf16 Bsl[128 * 32];
    const int tid = threadIdx.x;
    const int wave = tid >> 6, lane = tid & 63;
    const int lr = lane & 15, lk = lane >> 4;
    const int m0 = blockIdx.x * 128;
    const int n0 = blockIdx.y * 128;
    const int wm = (wave >> 1) * 64;
    const int wn = (wave & 1) * 64;
    const int srow = tid >> 2, sseg = tid & 3;

    f32x4 acc[4][4] = {};

    const bf16* aRow = A + (size_t)(m0 + srow) * K + sseg * 8;
    const bf16* bRow = B + (size_t)(n0 + srow) * K + sseg * 8;
    char* lA = (char*)Asl + tid * 16;
    char* lB = (char*)Bsl + tid * 16;
    const size_t rowK64 = (size_t)64 * K;

    for (int k0 = 0; k0 < K; k0 += 32) {
        GLDS(aRow + k0, lA);
        GLDS(aRow + k0 + rowK64, lA + 4096);
        GLDS(bRow + k0, lB);
        GLDS(bRow + k0 + rowK64, lB + 4096);
        __syncthreads();
        bf16x8 af[4], bfr[4];
#pragma unroll
        for (int i = 0; i < 4; ++i)
            af[i] = *(const bf16x8*)(Asl + (wm + i * 16 + lr) * 32 + lk * 8);
#pragma unroll
        for (int j = 0; j < 4; ++j)
            bfr[j] = *(const bf16x8*)(Bsl + (wn + j * 16 + lr) * 32 + lk * 8);
#pragma unroll
        for (int i = 0; i < 4; ++i)
#pragma unroll
            for (int j = 0; j < 4; ++j)
                acc[i][j] = __builtin_amdgcn_mfma_f32_16x16x32_bf16(af[i], bfr[j], acc[i][j], 0, 0, 0);
        __syncthreads();
    }

    if constexpr (MODE == 1) {
#pragma unroll
        for (int i = 0; i < 4; ++i)
#pragma unroll
            for (int j = 0; j < 4; ++j)
#pragma unroll
                for (int r = 0; r < 4; ++r) {
                    const int row = m0 + wm + i * 16 + lk * 4 + r;
                    const int col = n0 + wn + j * 16 + lr;
                    outf[(size_t)row * N + col] = acc[i][j][r];
                }
    } else {
        const int matn = n0 >> 10;   // 0=Q 1=K 2=V, uniform per block
#pragma unroll
        for (int i = 0; i < 4; ++i)
#pragma unroll
            for (int j = 0; j < 4; ++j)
#pragma unroll
                for (int r = 0; r < 4; ++r) {
                    const int row = m0 + wm + i * 16 + lk * 4 + r;
                    const int col = n0 + wn + j * 16 + lr;
                    float v = acc[i][j][r];
                    float p = __shfl_xor(v, 1);        // RoPE pair partner
                    const int e = col & 1023;
                    const int h = e >> 6;
                    const int dd = e & 63;
                    const int b = row >> 11;
                    const int s = row & 2047;
                    const size_t bhi = (size_t)(b * 16 + h);
                    if (matn == 2) {
                        vtb[(bhi * 64 + dd) * 2048 + s] = __float2bfloat16(v);
                    } else {
                        const float cs = cst[s * 32 + (dd >> 1)];
                        const float sn = snt[s * 32 + (dd >> 1)];
                        const float rv = (dd & 1) ? (p * sn + v * cs) : (v * cs - p * sn);
                        if (matn == 0)
                            qb[(bhi * 2048 + s) * 64 + dd] = __float2bfloat16(rv * 0.125f);
                        else
                            kb[(bhi * 2048 + s) * 64 + dd] = __float2bfloat16(rv);
                    }
                }
    }
}

// ---------------- causal flash attention ----------------
// Balanced pairing: block x processes q-strips (x, 31-x) -> 33 tile-visits per
// block, sharing one staged K/V stream (tiles 0..31-x) and the kf/vf LDS reads.
// Swapped QK^T: sc = mfma(kf, qf) gives P^T[k][q], lane owns one q-row
// (col=lr); softmax is in-lane + 2 shfls. P^T -> Pl[q][k] (8B writes), read
// back as PV B-operand (16B reads). 4 waves x 16 q-rows per strip.
__global__ __launch_bounds__(256) void attn_kernel(
    const bf16* __restrict__ qb, const bf16* __restrict__ kb,
    const bf16* __restrict__ vtb, bf16* __restrict__ attnb)
{
    __shared__ __align__(16) bf16 Kl[2][64 * 64];
    __shared__ __align__(16) bf16 Vl[2][64 * 64];
    __shared__ __align__(16) bf16 Pl[4][2][16][72];   // [wave][strip][q][k], 144B rows
    const int tid = threadIdx.x;
    const int wave = tid >> 6, lane = tid & 63;
    const int lr = lane & 15, lk = lane >> 4;
    const int tA = blockIdx.x;            // 0..15  (short strip)
    const int tB = 31 - tA;               // 16..31 (long strip)
    const int bh = blockIdx.y;
    const int qA = tA * 64 + wave * 16;
    const int qB = tB * 64 + wave * 16;

    const bf16* Qp = qb + (size_t)bh * 2048 * 64;
    const bf16* Kp = kb + (size_t)bh * 2048 * 64;
    const bf16* Vp = vtb + (size_t)bh * 64 * 2048;

    // staging geometry: 256 threads x 16B = 4KB = 32 rows of 128B per GLDS inst
    const int srow = tid >> 3;
    const int sseg = tid & 7;
    const int sw16 = (sseg ^ (srow & 7)) * 16;     // pre-swizzled byte offset in row
    const char* kg = (const char*)Kp + (size_t)srow * 128 + sw16;
    const char* vg = (const char*)Vp + (size_t)srow * 4096 + sw16;

#define STAGE(kt_, c_) do {                                              \
        const char* kgt = kg + (size_t)(kt_) * 8192;                     \
        GLDS(kgt,              &Kl[c_][0] + tid * 8);                    \
        GLDS(kgt + 32 * 128,   &Kl[c_][0] + 2048 + tid * 8);             \
        const char* vgt = vg + (size_t)(kt_) * 128;                      \
        GLDS(vgt,              &Vl[c_][0] + tid * 8);                    \
        GLDS(vgt + 32 * 4096,  &Vl[c_][0] + 2048 + tid * 8);             \
    } while (0)

    bf16x8 qfA[2], qfB[2];
#pragma unroll
    for (int ks = 0; ks < 2; ++ks) {
        qfA[ks] = *(const bf16x8*)(Qp + (qA + lr) * 64 + ks * 32 + lk * 8);
        qfB[ks] = *(const bf16x8*)(Qp + (qB + lr) * 64 + ks * 32 + lk * 8);
    }

    float mA = -1e30f, mB = -1e30f, sA = 0.f, sB = 0.f;
    f32x4 oA[4] = {}, oB[4] = {};

    STAGE(0, 0);

    const int xoff = (lr & 7) * 8;   // K/V swizzle: row&7 == lr&7 for rows j*16+lr

    for (int kt = 0; kt <= tB; ++kt) {
        const int c = kt & 1;
        const int kv0 = kt * 64;
        const bool doA = (kt <= tA);
        if (kt < tB) {
            STAGE(kt + 1, c ^ 1);
            asm volatile("s_waitcnt vmcnt(4)" ::: "memory");
        } else {
            asm volatile("s_waitcnt vmcnt(0)" ::: "memory");
        }
        __builtin_amdgcn_s_barrier();
        __builtin_amdgcn_sched_barrier(0);
        const bf16* Kc = &Kl[c][0];
        const bf16* Vc = &Vl[c][0];

        // ---- QK^T (swapped): scX[j][r] = P^T[k = j*16+lk*4+r][q = lr] ----
        f32x4 scB[4] = {}, scA[4] = {};
#pragma unroll
        for (int ks = 0; ks < 2; ++ks) {
            bf16x8 kf[4];
#pragma unroll
            for (int j = 0; j < 4; ++j)
                kf[j] = *(const bf16x8*)(Kc + (j * 16 + lr) * 64 + ((ks * 32 + lk * 8) ^ xoff));
            __builtin_amdgcn_s_setprio(1);
#pragma unroll
            for (int j = 0; j < 4; ++j)
                scB[j] = __builtin_amdgcn_mfma_f32_16x16x32_bf16(kf[j], qfB[ks], scB[j], 0, 0, 0);
            if (doA) {
#pragma unroll
                for (int j = 0; j < 4; ++j)
                    scA[j] = __builtin_amdgcn_mfma_f32_16x16x32_bf16(kf[j], qfA[ks], scA[j], 0, 0, 0);
            }
            __builtin_amdgcn_s_setprio(0);
        }

        // ---- softmax + P store (per strip) ----
        auto smx = [&](f32x4* sc, float& m, float& ssum, f32x4* o, int qX, bool diag, int st) {
            if (diag) {
#pragma unroll
                for (int j = 0; j < 4; ++j)
#pragma unroll
                    for (int r = 0; r < 4; ++r)
                        if (kv0 + j * 16 + lk * 4 + r > qX + lr) sc[j][r] = -1e30f;
            }
            float mt = sc[0][0];
#pragma unroll
            for (int j = 0; j < 4; ++j)
#pragma unroll
                for (int r = 0; r < 4; ++r) mt = fmaxf(mt, sc[j][r]);
            mt = fmaxf(mt, __shfl_xor(mt, 16));
            mt = fmaxf(mt, __shfl_xor(mt, 32));
            const float mn = fmaxf(m, mt);
            const float al = __expf(m - mn);
            m = mn;
            float ls = 0.f;
#pragma unroll
            for (int j = 0; j < 4; ++j) {
                float pv[4];
#pragma unroll
                for (int r = 0; r < 4; ++r) {
                    pv[r] = __expf(sc[j][r] - mn);
                    ls += pv[r];
                }
                union { bf16 h[4]; ushort4 s4; } u;
#pragma unroll
                for (int r = 0; r < 4; ++r) u.h[r] = __float2bfloat16(pv[r]);
                *(ushort4*)(&Pl[wave][st][lr][j * 16 + lk * 4]) = u.s4;
            }
            ssum = ssum * al + ls;
#pragma unroll
            for (int j = 0; j < 4; ++j)
#pragma unroll
                for (int r = 0; r < 4; ++r) o[j][r] *= al;
        };
        smx(scB, mB, sB, oB, qB, kt == tB, 1);
        if (doA) smx(scA, mA, sA, oA, qA, kt == tA, 0);

        // ---- PV: oX[j] (= O^T[d][q]) += mfma(vf, pfX) ; vf shared ----
#pragma unroll
        for (int ks = 0; ks < 2; ++ks) {
            const bf16x8 pfB = *(const bf16x8*)(&Pl[wave][1][lr][ks * 32 + lk * 8]);
            bf16x8 pfA = pfB;
            if (doA) pfA = *(const bf16x8*)(&Pl[wave][0][lr][ks * 32 + lk * 8]);
            __builtin_amdgcn_s_setprio(1);
#pragma unroll
            for (int j = 0; j < 4; ++j) {
                bf16x8 vf = *(const bf16x8*)(Vc + (j * 16 + lr) * 64 + ((ks * 32 + lk * 8) ^ xoff));
                oB[j] = __builtin_amdgcn_mfma_f32_16x16x32_bf16(vf, pfB, oB[j], 0, 0, 0);
                if (doA)
                    oA[j] = __builtin_amdgcn_mfma_f32_16x16x32_bf16(vf, pfA, oA[j], 0, 0, 0);
            }
            __builtin_amdgcn_s_setprio(0);
        }
        __builtin_amdgcn_sched_barrier(0);
        __builtin_amdgcn_s_barrier();
    }

    const int b = bh >> 4, h = bh & 15;
    auto epi = [&](float ssum, f32x4* o, int qX) {
        float s = ssum;
        s += __shfl_xor(s, 16);
        s += __shfl_xor(s, 32);
        const float inv = 1.0f / s;
        const int qq = qX + lr;
        bf16* dst = attnb + (size_t)(b * 2048 + qq) * 1024 + h * 64 + lk * 4;
#pragma unroll
        for (int j = 0; j < 4; ++j) {
            union { bf16 h4[4]; ushort4 s4; } u;
#pragma unroll
            for (int r = 0; r < 4; ++r) u.h4[r] = __float2bfloat16(o[j][r] * inv);
            *(ushort4*)(dst + j * 16) = u.s4;
        }
    };
    epi(sA, oA, qA);
    epi(sB, oB, qB);
#undef STAGE
}

// ---------------- launch ----------------
extern "C" void kernel_launch(void* const* d_in, const int* in_sizes, int n_in,
                              void* d_out, int out_size, void* d_ws, size_t ws_size,
                              hipStream_t stream)
{
    const float* x   = (const float*)d_in[0];
    const float* wq  = (const float*)d_in[1];
    const float* wk  = (const float*)d_in[2];
    const float* wv  = (const float*)d_in[3];
    const float* wo  = (const float*)d_in[4];
    const int*   pos = (const int*)d_in[5];
    const void* theta = d_in[6];

    char* ws = (char*)d_ws;
    bf16* xb    = (bf16*)(ws + OFF_XB);
    bf16* attnb = (bf16*)(ws + OFF_XB);    // reuse: xb consumed before attn writes
    bf16* wqkvb = (bf16*)(ws + OFF_WQKVB);
    bf16* wob   = (bf16*)(ws + OFF_WOB);
    bf16* qb    = (bf16*)(ws + OFF_QB);
    bf16* kb    = (bf16*)(ws + OFF_KB);
    bf16* vtb   = (bf16*)(ws + OFF_VTB);
    float* cst  = (float*)(ws + OFF_CS);
    float* snt  = (float*)(ws + OFF_SN);

    prep_kernel<<<dim3(4096, 5), 256, 0, stream>>>(x, wq, wk, wv, wo, xb, wqkvb, wob);
    rope_table_kernel<<<256, 256, 0, stream>>>(pos, theta, cst, snt);
    gemm_bt<0><<<dim3(32, 24), 256, 0, stream>>>(xb, wqkvb, 1024, 3072, nullptr,
                                                 qb, kb, vtb, cst, snt);
    attn_kernel<<<dim3(16, 32), 256, 0, stream>>>(qb, kb, vtb, attnb);
    gemm_bt<1><<<dim3(32, 8), 256, 0, stream>>>(attnb, wob, 1024, 1024, (float*)d_out,
                                                nullptr, nullptr, nullptr, nullptr, nullptr);
}